// Round 2
// baseline (143.804 us; speedup 1.0000x reference)
//
#include <hip/hip_runtime.h>

// out[i,j] = (z[i,:] . w) * w[j] + bias[j], all f32.
// S = 65536, B = 1024. Fused single kernel: one block per row.
// Traffic floor: 256 MB read (z) + 256 MB write (out) = 512 MB -> ~81 us @ 6.3 TB/s.

#define SDIM 65536
#define S4   (SDIM / 4)   // 16384 float4 per row
#define BLK  512

__global__ __launch_bounds__(BLK) void fused_fft_layer_kernel(
    const float* __restrict__ z,
    const float* __restrict__ w,
    const float* __restrict__ bias,
    float* __restrict__ out)
{
    const int row = blockIdx.x;
    const float4* __restrict__ zrow =
        reinterpret_cast<const float4*>(z + (size_t)row * SDIM);
    const float4* __restrict__ w4 = reinterpret_cast<const float4*>(w);
    const float4* __restrict__ b4 = reinterpret_cast<const float4*>(bias);
    float4* __restrict__ orow =
        reinterpret_cast<float4*>(out + (size_t)row * SDIM);

    // ---- phase 1: dot(z[row,:], w) ----
    float acc = 0.0f;
    for (int i = threadIdx.x; i < S4; i += BLK) {
        float4 a = zrow[i];
        float4 b = w4[i];
        acc += a.x * b.x + a.y * b.y + a.z * b.z + a.w * b.w;
    }

    #pragma unroll
    for (int off = 32; off > 0; off >>= 1)
        acc += __shfl_down(acc, off, 64);

    __shared__ float smem[BLK / 64];
    __shared__ float s_bcast;
    const int lane = threadIdx.x & 63;
    const int wid  = threadIdx.x >> 6;
    if (lane == 0) smem[wid] = acc;
    __syncthreads();
    if (threadIdx.x == 0) {
        float t = 0.0f;
        #pragma unroll
        for (int i = 0; i < BLK / 64; ++i) t += smem[i];
        s_bcast = t;
    }
    __syncthreads();
    const float s = s_bcast;

    // ---- phase 2: out[row,j] = s * w[j] + bias[j] ----
    for (int i = threadIdx.x; i < S4; i += BLK) {
        float4 wv = w4[i];
        float4 bv = b4[i];
        float4 r;
        r.x = fmaf(s, wv.x, bv.x);
        r.y = fmaf(s, wv.y, bv.y);
        r.z = fmaf(s, wv.z, bv.z);
        r.w = fmaf(s, wv.w, bv.w);
        orow[i] = r;
    }
}

extern "C" void kernel_launch(void* const* d_in, const int* in_sizes, int n_in,
                              void* d_out, int out_size, void* d_ws, size_t ws_size,
                              hipStream_t stream)
{
    const float* z    = (const float*)d_in[0];
    const float* w    = (const float*)d_in[1];  // (1,S,1) flat == (S,)
    const float* bias = (const float*)d_in[2];
    float* out = (float*)d_out;

    const int B = in_sizes[0] / SDIM;           // 1024

    fused_fft_layer_kernel<<<B, BLK, 0, stream>>>(z, w, bias, out);
}

// Round 4
// 102.261 us; speedup vs baseline: 1.4062x; 1.4062x over previous
//
#include <hip/hip_runtime.h>

// out[i,j] = (z[i,:] . w) * w[j] + bias[j], all f32.
// S = 65536, B = 1024.
// Split: kernel 1 computes scal = z @ w (read-bound, 256 MB),
//        kernel 2 writes out = scal (x) w + bias (write-bound, 256 MB, NT stores
//        so out doesn't evict z from the 256 MB Infinity Cache across replays).

#define SDIM 65536
#define S4   (SDIM / 4)   // 16384 float4 per row
#define BLK  512

// clang-native 16B vector (HIP float4 is a class; the NT builtin needs this)
typedef float floatx4 __attribute__((ext_vector_type(4)));

__global__ __launch_bounds__(BLK) void row_dot_kernel(
    const float* __restrict__ z,
    const float* __restrict__ w,
    float* __restrict__ scal)
{
    const int row = blockIdx.x;
    const floatx4* __restrict__ zrow =
        reinterpret_cast<const floatx4*>(z + (size_t)row * SDIM);
    const floatx4* __restrict__ w4 = reinterpret_cast<const floatx4*>(w);

    // 16384 float4 / 512 threads = 32 iters/thread; unroll 4 -> 8 loads in
    // flight, 4 independent accumulator chains.
    float acc0 = 0.f, acc1 = 0.f, acc2 = 0.f, acc3 = 0.f;
    for (int i = threadIdx.x; i < S4; i += 4 * BLK) {
        floatx4 a0 = zrow[i];
        floatx4 a1 = zrow[i + BLK];
        floatx4 a2 = zrow[i + 2 * BLK];
        floatx4 a3 = zrow[i + 3 * BLK];
        floatx4 b0 = w4[i];
        floatx4 b1 = w4[i + BLK];
        floatx4 b2 = w4[i + 2 * BLK];
        floatx4 b3 = w4[i + 3 * BLK];
        acc0 += a0.x * b0.x + a0.y * b0.y + a0.z * b0.z + a0.w * b0.w;
        acc1 += a1.x * b1.x + a1.y * b1.y + a1.z * b1.z + a1.w * b1.w;
        acc2 += a2.x * b2.x + a2.y * b2.y + a2.z * b2.z + a2.w * b2.w;
        acc3 += a3.x * b3.x + a3.y * b3.y + a3.z * b3.z + a3.w * b3.w;
    }
    float acc = (acc0 + acc1) + (acc2 + acc3);

    #pragma unroll
    for (int off = 32; off > 0; off >>= 1)
        acc += __shfl_down(acc, off, 64);

    __shared__ float smem[BLK / 64];
    const int lane = threadIdx.x & 63;
    const int wid  = threadIdx.x >> 6;
    if (lane == 0) smem[wid] = acc;
    __syncthreads();
    if (threadIdx.x == 0) {
        float t = 0.f;
        #pragma unroll
        for (int i = 0; i < BLK / 64; ++i) t += smem[i];
        scal[row] = t;
    }
}

// 4 blocks per row, 256 threads each: block covers 4096 float4 of one row.
#define OBLK   256
#define CHUNK4 (S4 / 4)   // 4096 float4 per block

__global__ __launch_bounds__(OBLK) void outer_kernel(
    const float* __restrict__ scal,
    const float* __restrict__ w,
    const float* __restrict__ bias,
    float* __restrict__ out)
{
    const int row   = blockIdx.x >> 2;
    const int chunk = blockIdx.x & 3;
    const int base  = chunk * CHUNK4;

    const float s = scal[row];
    const floatx4* __restrict__ w4 = reinterpret_cast<const floatx4*>(w) + base;
    const floatx4* __restrict__ b4 = reinterpret_cast<const floatx4*>(bias) + base;
    floatx4* __restrict__ orow =
        reinterpret_cast<floatx4*>(out + (size_t)row * SDIM) + base;

    // 4096 float4 / 256 threads = 16 iters; unroll 4.
    for (int i = threadIdx.x; i < CHUNK4; i += 4 * OBLK) {
        floatx4 w0 = w4[i];
        floatx4 w1 = w4[i + OBLK];
        floatx4 w2 = w4[i + 2 * OBLK];
        floatx4 w3 = w4[i + 3 * OBLK];
        floatx4 c0 = b4[i];
        floatx4 c1 = b4[i + OBLK];
        floatx4 c2 = b4[i + 2 * OBLK];
        floatx4 c3 = b4[i + 3 * OBLK];
        floatx4 r0, r1, r2, r3;
        r0.x = fmaf(s, w0.x, c0.x); r0.y = fmaf(s, w0.y, c0.y);
        r0.z = fmaf(s, w0.z, c0.z); r0.w = fmaf(s, w0.w, c0.w);
        r1.x = fmaf(s, w1.x, c1.x); r1.y = fmaf(s, w1.y, c1.y);
        r1.z = fmaf(s, w1.z, c1.z); r1.w = fmaf(s, w1.w, c1.w);
        r2.x = fmaf(s, w2.x, c2.x); r2.y = fmaf(s, w2.y, c2.y);
        r2.z = fmaf(s, w2.z, c2.z); r2.w = fmaf(s, w2.w, c2.w);
        r3.x = fmaf(s, w3.x, c3.x); r3.y = fmaf(s, w3.y, c3.y);
        r3.z = fmaf(s, w3.z, c3.z); r3.w = fmaf(s, w3.w, c3.w);
        // Non-temporal: keep `out` from evicting z in the Infinity Cache.
        __builtin_nontemporal_store(r0, &orow[i]);
        __builtin_nontemporal_store(r1, &orow[i + OBLK]);
        __builtin_nontemporal_store(r2, &orow[i + 2 * OBLK]);
        __builtin_nontemporal_store(r3, &orow[i + 3 * OBLK]);
    }
}

extern "C" void kernel_launch(void* const* d_in, const int* in_sizes, int n_in,
                              void* d_out, int out_size, void* d_ws, size_t ws_size,
                              hipStream_t stream)
{
    const float* z    = (const float*)d_in[0];
    const float* w    = (const float*)d_in[1];  // (1,S,1) flat == (S,)
    const float* bias = (const float*)d_in[2];
    float* out  = (float*)d_out;
    float* scal = (float*)d_ws;                 // B floats of scratch

    const int B = in_sizes[0] / SDIM;           // 1024

    row_dot_kernel<<<B, BLK, 0, stream>>>(z, w, scal);
    outer_kernel<<<B * 4, OBLK, 0, stream>>>(scal, w, bias, out);
}